// Round 9
// baseline (190.062 us; speedup 1.0000x reference)
//
#include <hip/hip_runtime.h>
#include <math.h>

#define BQ 4
#define CC 256
#define NN 512
#define HWD 65536
#define WW 256

typedef __attribute__((ext_vector_type(8))) _Float16 f16x8;
typedef __attribute__((ext_vector_type(4))) float f32x4;

// ---------------- fast-path ws byte offsets ----------------
#define OB_PART 1056768u          // [4*512][16][3] f32
#define OB_AH   2097152u          // [4][8][512][32] f16 (1 MB)
#define OB_BH   4194304u          // [4][8][65536][32] f16 (128 MB)
#define WS_REQ  138412032ull

#define GLDS16(g, l) __builtin_amdgcn_global_load_lds( \
    (const __attribute__((address_space(1))) void*)(g), \
    (__attribute__((address_space(3))) void*)(l), 16, 0, 0)

__device__ inline unsigned pk2h(float x0, float x1) {
    _Float16 h0 = (_Float16)x0, h1 = (_Float16)x1;
    unsigned short u0 = __builtin_bit_cast(unsigned short, h0);
    unsigned short u1 = __builtin_bit_cast(unsigned short, h1);
    return (unsigned)u0 | ((unsigned)u1 << 16);
}

// ================= prep: normalize + fp16 convert + k-blocked pack (A and B) =========
// blockIdx.x < 1024: B tile (odd batches of desc); >= 1024: A tile (even of kdesc).
__global__ __launch_bounds__(256) void k_prep16(
    const float* __restrict__ descB, const float* __restrict__ descA,
    _Float16* __restrict__ outB, _Float16* __restrict__ outA) {
    __shared__ float raw[CC * 64];
    __shared__ float sinv[64];
    int b = blockIdx.y;
    int bx = blockIdx.x;
    int tid = threadIdx.x;

    const float* S;
    _Float16* outH;
    int ld, rows_tot, mb;
    if (bx < 1024) {
        S = descB + (size_t)(2 * b + 1) * CC * HWD;
        outH = outB; ld = HWD; rows_tot = HWD; mb = bx * 64;
    } else {
        S = descA + (size_t)(2 * b) * CC * NN;
        outH = outA; ld = NN; rows_tot = NN; mb = (bx - 1024) * 64;
    }

    #pragma unroll
    for (int it = 0; it < 16; ++it) {
        int c = it * 16 + (tid >> 4);
        int m4 = (tid & 15) * 4;
        float4 v = *reinterpret_cast<const float4*>(S + (size_t)c * ld + mb + m4);
        *reinterpret_cast<float4*>(&raw[c * 64 + (m4 ^ (c & 60))]) = v;
    }
    __syncthreads();
    {
        int m = tid >> 2, part = tid & 3;
        float acc = 0.f;
        for (int i = 0; i < 64; ++i) {
            int c = part * 64 + i;
            float x = raw[c * 64 + (m ^ (c & 60))];
            acc = fmaf(x, x, acc);
        }
        acc += __shfl_xor(acc, 1);
        acc += __shfl_xor(acc, 2);
        if (part == 0) sinv[m] = 1.0f / fmaxf(sqrtf(acc), 1e-12f);
    }
    __syncthreads();
    int m = tid & 63, sub = tid >> 6;
    float iv = sinv[m];
    for (int kc = 0; kc < 8; ++kc) {
        int c0 = kc * 32 + sub * 8;
        unsigned hh[4];
        #pragma unroll
        for (int jp = 0; jp < 4; ++jp) {
            int c = c0 + jp * 2;
            int c1 = c + 1;
            float x0 = raw[c * 64 + (m ^ (c & 60))] * iv;
            float x1 = raw[c1 * 64 + (m ^ (c1 & 60))] * iv;
            hh[jp] = pk2h(x0, x1);
        }
        size_t base = ((size_t)(b * 8 + kc) * rows_tot + mb + m) * 32 + sub * 8;
        *reinterpret_cast<uint4*>(outH + base) = make_uint4(hh[0], hh[1], hh[2], hh[3]);
    }
}

// ================= main: single-pass fp16 MFMA GEMM + fused fixed-max softmax =======
// Grid 256 blocks: block = (b, chunk, nt). Tile 128n x 256m/step, m-chunk 4096.
// Wave grid 1x8: each wave owns full 128n x distinct 32m strip -> NO duplicated
// B global loads across waves. A (8 kc slices) resident in LDS (64KB), staged once,
// NO barriers in main loop. B frags register-direct from global, 4-buffer ring
// (&3 is phase-aligned since 8 kc/ms == 0 mod 4 -- the %3 ring was the r8 bug),
// distance-2 prefetch, counted vmcnt(4).
__global__ __launch_bounds__(512, 2) void k_main3(
    const _Float16* __restrict__ Ah, const _Float16* __restrict__ Bh,
    float* __restrict__ part) {
    __shared__ __align__(16) char smem[65536];

    int p = blockIdx.x;
    int xcd = p & 7, slot = p >> 3;
    int g = slot >> 2, nt = slot & 3;
    int pair = xcd * 8 + g;
    int bb = pair >> 4, chunk = pair & 15;
    int nbase = nt * 128;

    int tid = threadIdx.x;
    int w = tid >> 6, lane = tid & 63;
    int lrow = lane & 15, lkh = lane >> 4;
    int key = (lrow >> 1) & 3;

    // A staging: linear LDS dest + pre-swizzled source
    int sA = tid * 16;
    int rA = sA >> 6, slA = (sA >> 4) & 3;
    int seA = (rA << 5) + ((slA ^ ((rA >> 1) & 3)) << 3);
    int wb = w * 1024;

    // A frag ds_read offset (f16 elems): bank-swizzled; rt strides 16 rows (512 elems)
    int aoff = (lrow << 5) + ((lkh ^ key) << 3);
    // B frag global offset (f16 elems): wave-distinct 32m strip
    int boffG = ((w * 32 + lrow) << 5) + (lkh << 3);

    // ---- prologue: stage all A slices; load B for phases 0,1 ----
    #pragma unroll
    for (int kc = 0; kc < 8; ++kc) {
        size_t aB = ((size_t)(bb * 8 + kc) * 512 + nbase) * 32;
        GLDS16(Ah + aB + seA, smem + kc * 8192 + wb);
    }
    f16x8 breg[4][2];
    #define BLOAD(buf, ms, kc) do {                                             \
        size_t bB = ((size_t)(bb * 8 + (kc)) * 65536 + (size_t)chunk * 4096     \
                     + (size_t)(ms) * 256) * 32 + boffG;                        \
        const _Float16* bp = Bh + bB;                                           \
        breg[buf][0] = *reinterpret_cast<const f16x8*>(bp);                     \
        breg[buf][1] = *reinterpret_cast<const f16x8*>(bp + 512);               \
    } while (0)
    BLOAD(0, 0, 0);
    BLOAD(1, 0, 1);
    asm volatile("s_waitcnt vmcnt(0)" ::: "memory");
    __syncthreads();

    float s_[8][4], su_[8][4], sv_[8][4];
    #pragma unroll
    for (int i = 0; i < 8; ++i)
        #pragma unroll
        for (int j = 0; j < 4; ++j) { s_[i][j] = 0.f; su_[i][j] = 0.f; sv_[i][j] = 0.f; }

    for (int ms = 0; ms < 16; ++ms) {
        f32x4 acc[8][2];
        #pragma unroll
        for (int i = 0; i < 8; ++i)
            #pragma unroll
            for (int j = 0; j < 2; ++j) acc[i][j] = (f32x4){0.f, 0.f, 0.f, 0.f};

        #pragma unroll
        for (int kc = 0; kc < 8; ++kc) {
            // ---- A frag ds_reads issued BEFORE the vmcnt fence (LDS is stable) ----
            const _Float16* base = (const _Float16*)(smem + kc * 8192);
            f16x8 ah[8];
            #pragma unroll
            for (int rt = 0; rt < 8; ++rt)
                ah[rt] = *reinterpret_cast<const f16x8*>(base + aoff + rt * 512);

            // ---- prefetch phase p+2 into breg[(kc+2)&3]; counted wait ----
            // (phase p = ms*8+kc; kc&3 == p&3 because 8 == 0 mod 4)
            int nkc = kc + 2;
            int nms = ms + (nkc >> 3);
            nkc &= 7;
            if (nms < 16) {
                BLOAD((kc + 2) & 3, nms, nkc);
                asm volatile("s_waitcnt vmcnt(4)" ::: "memory");   // breg[kc&3] ready
            } else if (kc == 6) {
                asm volatile("s_waitcnt vmcnt(2)" ::: "memory");
            } else {
                asm volatile("s_waitcnt vmcnt(0)" ::: "memory");
            }

            __builtin_amdgcn_s_setprio(1);
            #pragma unroll
            for (int rt = 0; rt < 8; ++rt)
                #pragma unroll
                for (int ct = 0; ct < 2; ++ct)
                    acc[rt][ct] = __builtin_amdgcn_mfma_f32_16x16x32_f16(
                        ah[rt], breg[kc & 3][ct], acc[rt][ct], 0, 0, 0);
            __builtin_amdgcn_s_setprio(0);
        }

        // fused softmax accumulation: p = exp2(144.27*(dot-1)), fixed max (cos <= 1)
        float vstep = (float)(chunk * 16 + ms);
        #pragma unroll
        for (int rt = 0; rt < 8; ++rt) {
            #pragma unroll
            for (int reg = 0; reg < 4; ++reg) {
                float ts = 0.f, tu = 0.f;
                #pragma unroll
                for (int ct = 0; ct < 2; ++ct) {
                    float L = acc[rt][ct][reg];
                    float pz = exp2f(fmaf(L, 144.2695040889f, -144.2695040889f));
                    ts += pz;
                    tu = fmaf(pz, (float)(w * 32 + ct * 16 + lrow), tu);
                }
                s_[rt][reg] += ts;
                su_[rt][reg] += tu;
                sv_[rt][reg] = fmaf(vstep, ts, sv_[rt][reg]);
            }
        }
    }
    #undef BLOAD

    // ---- cross-lane (16 lrow) reduce, then cross-wave reduce through LDS ----
    __syncthreads();   // all waves done with A slices before smem reuse
    float* lred = (float*)smem;   // [8 waves][128 n_local][3]
    #pragma unroll
    for (int rt = 0; rt < 8; ++rt) {
        #pragma unroll
        for (int reg = 0; reg < 4; ++reg) {
            float a = s_[rt][reg], b2 = su_[rt][reg], c2 = sv_[rt][reg];
            #pragma unroll
            for (int o = 1; o < 16; o <<= 1) {
                a += __shfl_xor(a, o);
                b2 += __shfl_xor(b2, o);
                c2 += __shfl_xor(c2, o);
            }
            if (lrow == 0) {
                int nl = rt * 16 + lkh * 4 + reg;
                lred[(w * 128 + nl) * 3 + 0] = a;
                lred[(w * 128 + nl) * 3 + 1] = b2;
                lred[(w * 128 + nl) * 3 + 2] = c2;
            }
        }
    }
    __syncthreads();
    if (tid < 128) {
        int nl = tid;
        float a = 0.f, b2 = 0.f, c2 = 0.f;
        #pragma unroll
        for (int q = 0; q < 8; ++q) {
            const float* p2 = &lred[(q * 128 + nl) * 3];
            a += p2[0]; b2 += p2[1]; c2 += p2[2];
        }
        int n = nbase + nl;
        float* dst = part + ((size_t)(bb * 512 + n) * 16 + chunk) * 3;
        dst[0] = a; dst[1] = b2; dst[2] = c2;
    }
}

// ================= finish: merge partials + coords + packed-f16 bilinear dot =========
__global__ __launch_bounds__(256) void k_finish3(
    const float* __restrict__ kscores, const float* __restrict__ sdense,
    const _Float16* __restrict__ AH, const _Float16* __restrict__ BH,
    const float* __restrict__ part, float* __restrict__ out) {
    int bn = blockIdx.x;
    int b = bn >> 9, n = bn & 511;
    int tid = threadIdx.x;
    __shared__ float sw[4];
    __shared__ int sm[4];
    __shared__ float sps;
    __shared__ float red[4];

    if (tid == 0) {
        const float* pp = part + (size_t)bn * 48;
        float S = 0.f, SU = 0.f, SV = 0.f;
        for (int k = 0; k < 16; ++k) {
            S += pp[k * 3]; SU += pp[k * 3 + 1]; SV += pp[k * 3 + 2];
        }
        float u = SU / S, v = SV / S;
        out[bn * 2 + 0] = u;
        out[bn * 2 + 1] = v;

        float uc = fminf(fmaxf(u, 0.f), 255.f);
        float vc = fminf(fmaxf(v, 0.f), 255.f);
        float u0 = floorf(uc), v0 = floorf(vc);
        float u1 = fminf(u0 + 1.f, 255.f), v1 = fminf(v0 + 1.f, 255.f);
        float wu = uc - u0, wv = vc - v0;
        int i00 = (int)v0 * WW + (int)u0;
        int i01 = (int)v0 * WW + (int)u1;
        int i10 = (int)v1 * WW + (int)u0;
        int i11 = (int)v1 * WW + (int)u1;
        sw[0] = (1.f - wv) * (1.f - wu); sw[1] = (1.f - wv) * wu;
        sw[2] = wv * (1.f - wu);         sw[3] = wv * wu;
        sm[0] = i00; sm[1] = i01; sm[2] = i10; sm[3] = i11;

        const float* sd = sdense + (size_t)(2 * b + 1) * HWD;
        sps = sw[0] * sd[i00] + sw[1] * sd[i01] + sw[2] * sd[i10] + sw[3] * sd[i11];
    }
    __syncthreads();

    // packed, normalized f16 reads: column of AH / 4 corners of BH (8x64B contiguous)
    int kc = tid >> 5, e = tid & 31;
    float a = (float)AH[((size_t)(b * 8 + kc) * 512 + n) * 32 + e];
    float pdc = 0.f;
    #pragma unroll
    for (int wq = 0; wq < 4; ++wq) {
        float bv = (float)BH[((size_t)(b * 8 + kc) * 65536 + sm[wq]) * 32 + e];
        pdc = fmaf(sw[wq], bv, pdc);
    }
    float t = a * pdc;
    #pragma unroll
    for (int o = 1; o < 64; o <<= 1) t += __shfl_xor(t, o);
    if ((tid & 63) == 0) red[tid >> 6] = t;
    __syncthreads();
    if (tid == 0) {
        float dot = red[0] + red[1] + red[2] + red[3];
        float dms = dot * (1.0f / 256.0f);
        float wgt = 0.5f * (dms + 1.0f) * kscores[(size_t)(2 * b) * NN + n] * sps;
        out[BQ * NN * 2 + bn] = wgt;
    }
}

// ===================================================================================
// ======================= fallback path (round-1, small ws) =========================
// ===================================================================================
#define MCHUNKS 16
#define MLEN (HWD / MCHUNKS)
#define TN 64
#define TM 256
#define CK 16
#define WS_INVT 0
#define WS_INVS (BQ * HWD)
#define WS_PART (WS_INVS + BQ * NN)

__global__ void fb_invt(const float* __restrict__ desc, float* __restrict__ ws) {
    int gid = blockIdx.x * blockDim.x + threadIdx.x;
    int b = gid >> 14;
    int m4 = (gid & 16383) << 2;
    const float* base = desc + (size_t)(2 * b + 1) * CC * HWD + m4;
    float ax = 0.f, ay = 0.f, az = 0.f, aw = 0.f;
    #pragma unroll 4
    for (int c = 0; c < CC; ++c) {
        float4 v = *reinterpret_cast<const float4*>(base + (size_t)c * HWD);
        ax = fmaf(v.x, v.x, ax); ay = fmaf(v.y, v.y, ay);
        az = fmaf(v.z, v.z, az); aw = fmaf(v.w, v.w, aw);
    }
    float4 r;
    r.x = 1.0f / fmaxf(sqrtf(ax), 1e-12f);
    r.y = 1.0f / fmaxf(sqrtf(ay), 1e-12f);
    r.z = 1.0f / fmaxf(sqrtf(az), 1e-12f);
    r.w = 1.0f / fmaxf(sqrtf(aw), 1e-12f);
    *reinterpret_cast<float4*>(ws + WS_INVT + b * HWD + m4) = r;
}

__global__ void fb_invs(const float* __restrict__ kdesc, float* __restrict__ ws) {
    int gid = blockIdx.x * blockDim.x + threadIdx.x;
    int b = gid >> 9;
    int n = gid & 511;
    const float* base = kdesc + (size_t)(2 * b) * CC * NN + n;
    float acc = 0.f;
    for (int c = 0; c < CC; ++c) {
        float v = base[(size_t)c * NN];
        acc = fmaf(v, v, acc);
    }
    ws[WS_INVS + b * NN + n] = 1.0f / fmaxf(sqrtf(acc), 1e-12f);
}

__global__ __launch_bounds__(256) void fb_main(
    const float* __restrict__ kdesc, const float* __restrict__ desc,
    const float* __restrict__ ws, float* __restrict__ part) {
    __shared__ float As[CK][TN];
    __shared__ float Bs[CK][TM];
    int chunk = blockIdx.x, ntile = blockIdx.y, b = blockIdx.z;
    int tid = threadIdx.x;
    int tn = tid >> 5, tm = tid & 31;
    int nbase = ntile * TN;
    const float* Ag = kdesc + (size_t)(2 * b) * CC * NN + nbase;
    const float* Bg = desc + (size_t)(2 * b + 1) * CC * HWD + (size_t)chunk * MLEN;
    const float* invt = ws + WS_INVT + (size_t)b * HWD + (size_t)chunk * MLEN;
    float sA[8];
    #pragma unroll
    for (int r = 0; r < 8; ++r)
        sA[r] = ws[WS_INVS + b * NN + nbase + tn * 8 + r] * 100.0f;
    float mx[8], s[8], su[8], sv[8];
    #pragma unroll
    for (int r = 0; r < 8; ++r) { mx[r] = -1e30f; s[r] = 0.f; su[r] = 0.f; sv[r] = 0.f; }
    for (int mt = 0; mt < MLEN; mt += TM) {
        float acc[8][8];
        #pragma unroll
        for (int r = 0; r < 8; ++r)
            #pragma unroll
            for (int j = 0; j < 8; ++j) acc[r][j] = 0.f;
        for (int c0 = 0; c0 < CC; c0 += CK) {
            int ca = tid >> 4, na = (tid & 15) << 2;
            float4 va = *reinterpret_cast<const float4*>(Ag + (size_t)(c0 + ca) * NN + na);
            int cb = tid >> 6, mb = (tid & 63) << 2;
            float4 vb[4];
            #pragma unroll
            for (int i = 0; i < 4; ++i)
                vb[i] = *reinterpret_cast<const float4*>(Bg + (size_t)(c0 + cb + 4 * i) * HWD + mt + mb);
            __syncthreads();
            *reinterpret_cast<float4*>(&As[ca][na]) = va;
            #pragma unroll
            for (int i = 0; i < 4; ++i)
                *reinterpret_cast<float4*>(&Bs[cb + 4 * i][mb]) = vb[i];
            __syncthreads();
            #pragma unroll
            for (int cc = 0; cc < CK; ++cc) {
                float a[8], bv[8];
                *reinterpret_cast<float4*>(&a[0]) = *reinterpret_cast<const float4*>(&As[cc][tn * 8]);
                *reinterpret_cast<float4*>(&a[4]) = *reinterpret_cast<const float4*>(&As[cc][tn * 8 + 4]);
                *reinterpret_cast<float4*>(&bv[0]) = *reinterpret_cast<const float4*>(&Bs[cc][tm * 8]);
                *reinterpret_cast<float4*>(&bv[4]) = *reinterpret_cast<const float4*>(&Bs[cc][tm * 8 + 4]);
                #pragma unroll
                for (int r = 0; r < 8; ++r)
                    #pragma unroll
                    for (int j = 0; j < 8; ++j)
                        acc[r][j] = fmaf(a[r], bv[j], acc[r][j]);
            }
        }
        float it[8];
        *reinterpret_cast<float4*>(&it[0]) = *reinterpret_cast<const float4*>(invt + mt + tm * 8);
        *reinterpret_cast<float4*>(&it[4]) = *reinterpret_cast<const float4*>(invt + mt + tm * 8 + 4);
        int mg0 = chunk * MLEN + mt + tm * 8;
        float vt = (float)(mg0 >> 8);
        float ub = (float)(tm * 8);
        #pragma unroll
        for (int r = 0; r < 8; ++r) {
            float L[8];
            #pragma unroll
            for (int j = 0; j < 8; ++j) L[j] = acc[r][j] * (sA[r] * it[j]);
            float tmax = L[0];
            #pragma unroll
            for (int j = 1; j < 8; ++j) tmax = fmaxf(tmax, L[j]);
            #pragma unroll
            for (int o = 1; o < 32; o <<= 1) tmax = fmaxf(tmax, __shfl_xor(tmax, o));
            float newm = fmaxf(mx[r], tmax);
            float ts = 0.f, tu = 0.f;
            #pragma unroll
            for (int j = 0; j < 8; ++j) {
                float pz = __expf(L[j] - newm);
                ts += pz;
                tu = fmaf(pz, ub + (float)j, tu);
            }
            #pragma unroll
            for (int o = 1; o < 32; o <<= 1) {
                ts += __shfl_xor(ts, o);
                tu += __shfl_xor(tu, o);
            }
            float f = __expf(mx[r] - newm);
            s[r]  = fmaf(s[r], f, ts);
            su[r] = fmaf(su[r], f, tu);
            sv[r] = fmaf(sv[r], f, vt * ts);
            mx[r] = newm;
        }
    }
    if (tm == 0) {
        #pragma unroll
        for (int r = 0; r < 8; ++r) {
            int n = nbase + tn * 8 + r;
            float4 o4 = make_float4(mx[r], s[r], su[r], sv[r]);
            *reinterpret_cast<float4*>(part + ((size_t)(b * NN + n) * MCHUNKS + chunk) * 4) = o4;
        }
    }
}

__global__ void fb_finish(const float* __restrict__ kscores,
                          const float* __restrict__ kdesc,
                          const float* __restrict__ sdense,
                          const float* __restrict__ desc,
                          const float* __restrict__ ws,
                          float* __restrict__ out) {
    int bn = blockIdx.x;
    int b = bn >> 9, n = bn & 511;
    int tid = threadIdx.x;
    __shared__ float swf[8];
    __shared__ int sidx[4];
    __shared__ float red[4];
    if (tid == 0) {
        const float* pp = ws + WS_PART + (size_t)bn * MCHUNKS * 4;
        float M = -1e30f;
        for (int k = 0; k < MCHUNKS; ++k) M = fmaxf(M, pp[4 * k]);
        float S = 0.f, SU = 0.f, SV = 0.f;
        for (int k = 0; k < MCHUNKS; ++k) {
            float f = __expf(pp[4 * k] - M);
            S  = fmaf(pp[4 * k + 1], f, S);
            SU = fmaf(pp[4 * k + 2], f, SU);
            SV = fmaf(pp[4 * k + 3], f, SV);
        }
        float u = SU / S, v = SV / S;
        out[bn * 2 + 0] = u;
        out[bn * 2 + 1] = v;
        float uc = fminf(fmaxf(u, 0.f), 255.f);
        float vc = fminf(fmaxf(v, 0.f), 255.f);
        float u0 = floorf(uc), v0 = floorf(vc);
        float u1 = fminf(u0 + 1.f, 255.f), v1 = fminf(v0 + 1.f, 255.f);
        float wu = uc - u0, wv = vc - v0;
        int i00 = (int)v0 * WW + (int)u0;
        int i01 = (int)v0 * WW + (int)u1;
        int i10 = (int)v1 * WW + (int)u0;
        int i11 = (int)v1 * WW + (int)u1;
        float w00 = (1.f - wv) * (1.f - wu), w01 = (1.f - wv) * wu;
        float w10 = wv * (1.f - wu),         w11 = wv * wu;
        const float* sd = sdense + (size_t)(2 * b + 1) * HWD;
        float ps = w00 * sd[i00] + w01 * sd[i01] + w10 * sd[i10] + w11 * sd[i11];
        const float* it = ws + WS_INVT + (size_t)b * HWD;
        swf[0] = w00 * it[i00]; swf[1] = w01 * it[i01];
        swf[2] = w10 * it[i10]; swf[3] = w11 * it[i11];
        swf[4] = ps;
        sidx[0] = i00; sidx[1] = i01; sidx[2] = i10; sidx[3] = i11;
    }
    __syncthreads();
    int c = tid;
    const float* dcol = desc + (size_t)(2 * b + 1) * CC * HWD + (size_t)c * HWD;
    float pd = swf[0] * dcol[sidx[0]] + swf[1] * dcol[sidx[1]]
             + swf[2] * dcol[sidx[2]] + swf[3] * dcol[sidx[3]];
    float sc = kdesc[(size_t)(2 * b) * CC * NN + (size_t)c * NN + n];
    float t = pd * sc;
    #pragma unroll
    for (int o = 32; o > 0; o >>= 1) t += __shfl_xor(t, o);
    if ((tid & 63) == 0) red[tid >> 6] = t;
    __syncthreads();
    if (tid == 0) {
        float dot = red[0] + red[1] + red[2] + red[3];
        float invs = ws[WS_INVS + b * NN + n];
        float dms = dot * invs * (1.0f / 256.0f);
        float wgt = 0.5f * (dms + 1.0f) * kscores[(size_t)(2 * b) * NN + n] * swf[4];
        out[BQ * NN * 2 + bn] = wgt;
    }
}

// ===================================================================================
extern "C" void kernel_launch(void* const* d_in, const int* in_sizes, int n_in,
                              void* d_out, int out_size, void* d_ws, size_t ws_size,
                              hipStream_t stream) {
    const float* kscores = (const float*)d_in[0];  // (8,1,512)
    const float* kdesc   = (const float*)d_in[1];  // (8,256,512)
    const float* sdense  = (const float*)d_in[2];  // (8,1,256,256)
    const float* desc    = (const float*)d_in[3];  // (8,256,256,256)
    float* out = (float*)d_out;
    char* wsb = (char*)d_ws;
    float* wsf = (float*)d_ws;

    if (ws_size >= WS_REQ) {
        _Float16* AH = (_Float16*)(wsb + OB_AH);
        _Float16* BH = (_Float16*)(wsb + OB_BH);
        float* part = (float*)(wsb + OB_PART);

        // combined prep: x<1024 -> B tiles (odd desc batches), x>=1024 -> A tiles
        hipLaunchKernelGGL(k_prep16, dim3(1024 + NN / 64, BQ), dim3(256), 0, stream,
                           desc, kdesc, BH, AH);
        hipLaunchKernelGGL(k_main3, dim3(256), dim3(512), 0, stream,
                           AH, BH, part);
        hipLaunchKernelGGL(k_finish3, dim3(BQ * NN), dim3(256), 0, stream,
                           kscores, sdense, AH, BH, part, out);
    } else {
        float* ws = wsf;
        hipLaunchKernelGGL(fb_invt, dim3(BQ * HWD / 4 / 256), dim3(256), 0, stream, desc, ws);
        hipLaunchKernelGGL(fb_invs, dim3(BQ * NN / 256), dim3(256), 0, stream, kdesc, ws);
        hipLaunchKernelGGL(fb_main, dim3(MCHUNKS, NN / TN, BQ), dim3(256), 0, stream,
                           kdesc, desc, ws, ws + WS_PART);
        hipLaunchKernelGGL(fb_finish, dim3(BQ * NN), dim3(256), 0, stream,
                           kscores, kdesc, sdense, desc, ws, out);
    }
}

// Round 10
// 184.184 us; speedup vs baseline: 1.0319x; 1.0319x over previous
//
#include <hip/hip_runtime.h>
#include <math.h>

#define BQ 4
#define CC 256
#define NN 512
#define HWD 65536
#define WW 256

typedef __attribute__((ext_vector_type(8))) _Float16 f16x8;
typedef __attribute__((ext_vector_type(4))) float f32x4;

// ---------------- fast-path ws byte offsets ----------------
#define OB_PART 1056768u          // [4*512][16][3] f32
#define OB_AH   2097152u          // [4][8][512][32] f16 (1 MB)
#define OB_BH   4194304u          // [4][8][65536][32] f16 (128 MB)
#define WS_REQ  138412032ull

#define GLDS16(g, l) __builtin_amdgcn_global_load_lds( \
    (const __attribute__((address_space(1))) void*)(g), \
    (__attribute__((address_space(3))) void*)(l), 16, 0, 0)

__device__ inline unsigned pk2h(float x0, float x1) {
    _Float16 h0 = (_Float16)x0, h1 = (_Float16)x1;
    unsigned short u0 = __builtin_bit_cast(unsigned short, h0);
    unsigned short u1 = __builtin_bit_cast(unsigned short, h1);
    return (unsigned)u0 | ((unsigned)u1 << 16);
}

// ================= prep: normalize + fp16 convert + k-blocked pack (A and B) =========
// blockIdx.x < 1024: B tile (odd batches of desc); >= 1024: A tile (even of kdesc).
__global__ __launch_bounds__(256) void k_prep16(
    const float* __restrict__ descB, const float* __restrict__ descA,
    _Float16* __restrict__ outB, _Float16* __restrict__ outA) {
    __shared__ float raw[CC * 64];
    __shared__ float sinv[64];
    int b = blockIdx.y;
    int bx = blockIdx.x;
    int tid = threadIdx.x;

    const float* S;
    _Float16* outH;
    int ld, rows_tot, mb;
    if (bx < 1024) {
        S = descB + (size_t)(2 * b + 1) * CC * HWD;
        outH = outB; ld = HWD; rows_tot = HWD; mb = bx * 64;
    } else {
        S = descA + (size_t)(2 * b) * CC * NN;
        outH = outA; ld = NN; rows_tot = NN; mb = (bx - 1024) * 64;
    }

    #pragma unroll
    for (int it = 0; it < 16; ++it) {
        int c = it * 16 + (tid >> 4);
        int m4 = (tid & 15) * 4;
        float4 v = *reinterpret_cast<const float4*>(S + (size_t)c * ld + mb + m4);
        *reinterpret_cast<float4*>(&raw[c * 64 + (m4 ^ (c & 60))]) = v;
    }
    __syncthreads();
    {
        int m = tid >> 2, part = tid & 3;
        float acc = 0.f;
        for (int i = 0; i < 64; ++i) {
            int c = part * 64 + i;
            float x = raw[c * 64 + (m ^ (c & 60))];
            acc = fmaf(x, x, acc);
        }
        acc += __shfl_xor(acc, 1);
        acc += __shfl_xor(acc, 2);
        if (part == 0) sinv[m] = 1.0f / fmaxf(sqrtf(acc), 1e-12f);
    }
    __syncthreads();
    int m = tid & 63, sub = tid >> 6;
    float iv = sinv[m];
    for (int kc = 0; kc < 8; ++kc) {
        int c0 = kc * 32 + sub * 8;
        unsigned hh[4];
        #pragma unroll
        for (int jp = 0; jp < 4; ++jp) {
            int c = c0 + jp * 2;
            int c1 = c + 1;
            float x0 = raw[c * 64 + (m ^ (c & 60))] * iv;
            float x1 = raw[c1 * 64 + (m ^ (c1 & 60))] * iv;
            hh[jp] = pk2h(x0, x1);
        }
        size_t base = ((size_t)(b * 8 + kc) * rows_tot + mb + m) * 32 + sub * 8;
        *reinterpret_cast<uint4*>(outH + base) = make_uint4(hh[0], hh[1], hh[2], hh[3]);
    }
}

// ================= main: single-pass fp16 MFMA GEMM + fused fixed-max softmax =======
// Grid 256 blocks: block = (b, chunk, nt). Tile 128n x 256m/step, m-chunk 4096.
// Wave grid 2wn x 4wm (r7 layout -- the r9 1x8 layout regressed). A (8 kc slices)
// resident in LDS (64KB) staged once -> NO barriers in main loop. B frags
// register-direct from global, 4-buffer ring (&3, phase-aligned: 8 kc == 0 mod 4),
// prefetch DISTANCE 3 (covers ~690cy of L2/L3 latency), counted vmcnt(12).
__global__ __launch_bounds__(512, 2) void k_main3(
    const _Float16* __restrict__ Ah, const _Float16* __restrict__ Bh,
    float* __restrict__ part) {
    __shared__ __align__(16) char smem[65536];

    int p = blockIdx.x;
    int xcd = p & 7, slot = p >> 3;
    int g = slot >> 2, nt = slot & 3;
    int pair = xcd * 8 + g;
    int bb = pair >> 4, chunk = pair & 15;
    int nbase = nt * 128;

    int tid = threadIdx.x;
    int w = tid >> 6, lane = tid & 63;
    int wn = w >> 2, wm = w & 3;
    int lrow = lane & 15, lkh = lane >> 4;
    int key = (lrow >> 1) & 3;

    // A staging: linear LDS dest + pre-swizzled source
    int sA = tid * 16;
    int rA = sA >> 6, slA = (sA >> 4) & 3;
    int seA = (rA << 5) + ((slA ^ ((rA >> 1) & 3)) << 3);
    int wb = w * 1024;

    // A frag ds_read offset (f16 elems): bank-swizzled
    int aoff = ((wn * 64 + lrow) << 5) + ((lkh ^ key) << 3);
    // B frag global offset (f16 elems): linear
    int boffG = ((wm * 64 + lrow) << 5) + (lkh << 3);

    // ---- prologue: stage all A slices; load B for phases 0,1,2 ----
    #pragma unroll
    for (int kc = 0; kc < 8; ++kc) {
        size_t aB = ((size_t)(bb * 8 + kc) * 512 + nbase) * 32;
        GLDS16(Ah + aB + seA, smem + kc * 8192 + wb);
    }
    f16x8 breg[4][4];
    #define BLOAD(buf, ms, kc) do {                                             \
        size_t bB = ((size_t)(bb * 8 + (kc)) * 65536 + (size_t)chunk * 4096     \
                     + (size_t)(ms) * 256) * 32 + boffG;                        \
        const _Float16* bp = Bh + bB;                                           \
        breg[buf][0] = *reinterpret_cast<const f16x8*>(bp);                     \
        breg[buf][1] = *reinterpret_cast<const f16x8*>(bp + 512);               \
        breg[buf][2] = *reinterpret_cast<const f16x8*>(bp + 1024);              \
        breg[buf][3] = *reinterpret_cast<const f16x8*>(bp + 1536);              \
    } while (0)
    BLOAD(0, 0, 0);
    BLOAD(1, 0, 1);
    BLOAD(2, 0, 2);
    asm volatile("s_waitcnt vmcnt(0)" ::: "memory");
    __syncthreads();

    float s_[4][4], su_[4][4], sv_[4][4];
    #pragma unroll
    for (int i = 0; i < 4; ++i)
        #pragma unroll
        for (int j = 0; j < 4; ++j) { s_[i][j] = 0.f; su_[i][j] = 0.f; sv_[i][j] = 0.f; }

    for (int ms = 0; ms < 16; ++ms) {
        f32x4 acc[4][4];
        #pragma unroll
        for (int i = 0; i < 4; ++i)
            #pragma unroll
            for (int j = 0; j < 4; ++j) acc[i][j] = (f32x4){0.f, 0.f, 0.f, 0.f};

        #pragma unroll
        for (int kc = 0; kc < 8; ++kc) {
            // ---- A frag ds_reads issued BEFORE the vmcnt fence (LDS is stable) ----
            const _Float16* base = (const _Float16*)(smem + kc * 8192);
            f16x8 ah[4];
            #pragma unroll
            for (int rt = 0; rt < 4; ++rt)
                ah[rt] = *reinterpret_cast<const f16x8*>(base + aoff + rt * 512);

            // ---- prefetch phase p+3 into breg[(kc+3)&3]; counted wait ----
            // (phase p = ms*8+kc; kc&3 == p&3 because 8 == 0 mod 4; distance 3 < 4 bufs)
            int npk = kc + 3;
            int nms = ms + (npk >> 3);
            int nkc = npk & 7;
            if (nms < 16) {
                BLOAD((kc + 3) & 3, nms, nkc);
                asm volatile("s_waitcnt vmcnt(12)" ::: "memory");  // breg[kc&3] ready
            } else if (kc == 5) {
                asm volatile("s_waitcnt vmcnt(8)" ::: "memory");
            } else if (kc == 6) {
                asm volatile("s_waitcnt vmcnt(4)" ::: "memory");
            } else {
                asm volatile("s_waitcnt vmcnt(0)" ::: "memory");
            }

            __builtin_amdgcn_s_setprio(1);
            #pragma unroll
            for (int rt = 0; rt < 4; ++rt)
                #pragma unroll
                for (int ct = 0; ct < 4; ++ct)
                    acc[rt][ct] = __builtin_amdgcn_mfma_f32_16x16x32_f16(
                        ah[rt], breg[kc & 3][ct], acc[rt][ct], 0, 0, 0);
            __builtin_amdgcn_s_setprio(0);
        }

        // fused softmax accumulation: p = exp2(144.27*(dot-1)), fixed max (cos <= 1)
        float vstep = (float)(chunk * 16 + ms);
        #pragma unroll
        for (int rt = 0; rt < 4; ++rt) {
            #pragma unroll
            for (int reg = 0; reg < 4; ++reg) {
                float ts = 0.f, tu = 0.f;
                #pragma unroll
                for (int ct = 0; ct < 4; ++ct) {
                    float L = acc[rt][ct][reg];
                    float pz = exp2f(fmaf(L, 144.2695040889f, -144.2695040889f));
                    ts += pz;
                    tu = fmaf(pz, (float)(wm * 64 + ct * 16 + lrow), tu);
                }
                s_[rt][reg] += ts;
                su_[rt][reg] += tu;
                sv_[rt][reg] = fmaf(vstep, ts, sv_[rt][reg]);
            }
        }
    }
    #undef BLOAD

    // ---- cross-lane (16 lrow) reduce, then cross-wm reduce through LDS ----
    __syncthreads();   // all waves done with A slices before smem reuse
    float* lred = (float*)smem;   // [8 waves][64 n_local][3]
    #pragma unroll
    for (int rt = 0; rt < 4; ++rt) {
        #pragma unroll
        for (int reg = 0; reg < 4; ++reg) {
            float a = s_[rt][reg], b2 = su_[rt][reg], c2 = sv_[rt][reg];
            #pragma unroll
            for (int o = 1; o < 16; o <<= 1) {
                a += __shfl_xor(a, o);
                b2 += __shfl_xor(b2, o);
                c2 += __shfl_xor(c2, o);
            }
            if (lrow == 0) {
                int nl = rt * 16 + lkh * 4 + reg;
                lred[(w * 64 + nl) * 3 + 0] = a;
                lred[(w * 64 + nl) * 3 + 1] = b2;
                lred[(w * 64 + nl) * 3 + 2] = c2;
            }
        }
    }
    __syncthreads();
    if (tid < 128) {
        int wnl = tid >> 6, nl = tid & 63;
        float a = 0.f, b2 = 0.f, c2 = 0.f;
        #pragma unroll
        for (int q = 0; q < 4; ++q) {
            const float* p2 = &lred[((wnl * 4 + q) * 64 + nl) * 3];
            a += p2[0]; b2 += p2[1]; c2 += p2[2];
        }
        int n = nbase + wnl * 64 + nl;
        float* dst = part + ((size_t)(bb * 512 + n) * 16 + chunk) * 3;
        dst[0] = a; dst[1] = b2; dst[2] = c2;
    }
}

// ================= finish: merge partials + coords + packed-f16 bilinear dot =========
__global__ __launch_bounds__(256) void k_finish3(
    const float* __restrict__ kscores, const float* __restrict__ sdense,
    const _Float16* __restrict__ AH, const _Float16* __restrict__ BH,
    const float* __restrict__ part, float* __restrict__ out) {
    int bn = blockIdx.x;
    int b = bn >> 9, n = bn & 511;
    int tid = threadIdx.x;
    __shared__ float sw[4];
    __shared__ int sm[4];
    __shared__ float sps;
    __shared__ float red[4];

    if (tid == 0) {
        const float* pp = part + (size_t)bn * 48;
        float S = 0.f, SU = 0.f, SV = 0.f;
        for (int k = 0; k < 16; ++k) {
            S += pp[k * 3]; SU += pp[k * 3 + 1]; SV += pp[k * 3 + 2];
        }
        float u = SU / S, v = SV / S;
        out[bn * 2 + 0] = u;
        out[bn * 2 + 1] = v;

        float uc = fminf(fmaxf(u, 0.f), 255.f);
        float vc = fminf(fmaxf(v, 0.f), 255.f);
        float u0 = floorf(uc), v0 = floorf(vc);
        float u1 = fminf(u0 + 1.f, 255.f), v1 = fminf(v0 + 1.f, 255.f);
        float wu = uc - u0, wv = vc - v0;
        int i00 = (int)v0 * WW + (int)u0;
        int i01 = (int)v0 * WW + (int)u1;
        int i10 = (int)v1 * WW + (int)u0;
        int i11 = (int)v1 * WW + (int)u1;
        sw[0] = (1.f - wv) * (1.f - wu); sw[1] = (1.f - wv) * wu;
        sw[2] = wv * (1.f - wu);         sw[3] = wv * wu;
        sm[0] = i00; sm[1] = i01; sm[2] = i10; sm[3] = i11;

        const float* sd = sdense + (size_t)(2 * b + 1) * HWD;
        sps = sw[0] * sd[i00] + sw[1] * sd[i01] + sw[2] * sd[i10] + sw[3] * sd[i11];
    }
    __syncthreads();

    // packed, normalized f16 reads: column of AH / 4 corners of BH (8x64B contiguous)
    int kc = tid >> 5, e = tid & 31;
    float a = (float)AH[((size_t)(b * 8 + kc) * 512 + n) * 32 + e];
    float pdc = 0.f;
    #pragma unroll
    for (int wq = 0; wq < 4; ++wq) {
        float bv = (float)BH[((size_t)(b * 8 + kc) * 65536 + sm[wq]) * 32 + e];
        pdc = fmaf(sw[wq], bv, pdc);
    }
    float t = a * pdc;
    #pragma unroll
    for (int o = 1; o < 64; o <<= 1) t += __shfl_xor(t, o);
    if ((tid & 63) == 0) red[tid >> 6] = t;
    __syncthreads();
    if (tid == 0) {
        float dot = red[0] + red[1] + red[2] + red[3];
        float dms = dot * (1.0f / 256.0f);
        float wgt = 0.5f * (dms + 1.0f) * kscores[(size_t)(2 * b) * NN + n] * sps;
        out[BQ * NN * 2 + bn] = wgt;
    }
}

// ===================================================================================
// ======================= fallback path (round-1, small ws) =========================
// ===================================================================================
#define MCHUNKS 16
#define MLEN (HWD / MCHUNKS)
#define TN 64
#define TM 256
#define CK 16
#define WS_INVT 0
#define WS_INVS (BQ * HWD)
#define WS_PART (WS_INVS + BQ * NN)

__global__ void fb_invt(const float* __restrict__ desc, float* __restrict__ ws) {
    int gid = blockIdx.x * blockDim.x + threadIdx.x;
    int b = gid >> 14;
    int m4 = (gid & 16383) << 2;
    const float* base = desc + (size_t)(2 * b + 1) * CC * HWD + m4;
    float ax = 0.f, ay = 0.f, az = 0.f, aw = 0.f;
    #pragma unroll 4
    for (int c = 0; c < CC; ++c) {
        float4 v = *reinterpret_cast<const float4*>(base + (size_t)c * HWD);
        ax = fmaf(v.x, v.x, ax); ay = fmaf(v.y, v.y, ay);
        az = fmaf(v.z, v.z, az); aw = fmaf(v.w, v.w, aw);
    }
    float4 r;
    r.x = 1.0f / fmaxf(sqrtf(ax), 1e-12f);
    r.y = 1.0f / fmaxf(sqrtf(ay), 1e-12f);
    r.z = 1.0f / fmaxf(sqrtf(az), 1e-12f);
    r.w = 1.0f / fmaxf(sqrtf(aw), 1e-12f);
    *reinterpret_cast<float4*>(ws + WS_INVT + b * HWD + m4) = r;
}

__global__ void fb_invs(const float* __restrict__ kdesc, float* __restrict__ ws) {
    int gid = blockIdx.x * blockDim.x + threadIdx.x;
    int b = gid >> 9;
    int n = gid & 511;
    const float* base = kdesc + (size_t)(2 * b) * CC * NN + n;
    float acc = 0.f;
    for (int c = 0; c < CC; ++c) {
        float v = base[(size_t)c * NN];
        acc = fmaf(v, v, acc);
    }
    ws[WS_INVS + b * NN + n] = 1.0f / fmaxf(sqrtf(acc), 1e-12f);
}

__global__ __launch_bounds__(256) void fb_main(
    const float* __restrict__ kdesc, const float* __restrict__ desc,
    const float* __restrict__ ws, float* __restrict__ part) {
    __shared__ float As[CK][TN];
    __shared__ float Bs[CK][TM];
    int chunk = blockIdx.x, ntile = blockIdx.y, b = blockIdx.z;
    int tid = threadIdx.x;
    int tn = tid >> 5, tm = tid & 31;
    int nbase = ntile * TN;
    const float* Ag = kdesc + (size_t)(2 * b) * CC * NN + nbase;
    const float* Bg = desc + (size_t)(2 * b + 1) * CC * HWD + (size_t)chunk * MLEN;
    const float* invt = ws + WS_INVT + (size_t)b * HWD + (size_t)chunk * MLEN;
    float sA[8];
    #pragma unroll
    for (int r = 0; r < 8; ++r)
        sA[r] = ws[WS_INVS + b * NN + nbase + tn * 8 + r] * 100.0f;
    float mx[8], s[8], su[8], sv[8];
    #pragma unroll
    for (int r = 0; r < 8; ++r) { mx[r] = -1e30f; s[r] = 0.f; su[r] = 0.f; sv[r] = 0.f; }
    for (int mt = 0; mt < MLEN; mt += TM) {
        float acc[8][8];
        #pragma unroll
        for (int r = 0; r < 8; ++r)
            #pragma unroll
            for (int j = 0; j < 8; ++j) acc[r][j] = 0.f;
        for (int c0 = 0; c0 < CC; c0 += CK) {
            int ca = tid >> 4, na = (tid & 15) << 2;
            float4 va = *reinterpret_cast<const float4*>(Ag + (size_t)(c0 + ca) * NN + na);
            int cb = tid >> 6, mb = (tid & 63) << 2;
            float4 vb[4];
            #pragma unroll
            for (int i = 0; i < 4; ++i)
                vb[i] = *reinterpret_cast<const float4*>(Bg + (size_t)(c0 + cb + 4 * i) * HWD + mt + mb);
            __syncthreads();
            *reinterpret_cast<float4*>(&As[ca][na]) = va;
            #pragma unroll
            for (int i = 0; i < 4; ++i)
                *reinterpret_cast<float4*>(&Bs[cb + 4 * i][mb]) = vb[i];
            __syncthreads();
            #pragma unroll
            for (int cc = 0; cc < CK; ++cc) {
                float a[8], bv[8];
                *reinterpret_cast<float4*>(&a[0]) = *reinterpret_cast<const float4*>(&As[cc][tn * 8]);
                *reinterpret_cast<float4*>(&a[4]) = *reinterpret_cast<const float4*>(&As[cc][tn * 8 + 4]);
                *reinterpret_cast<float4*>(&bv[0]) = *reinterpret_cast<const float4*>(&Bs[cc][tm * 8]);
                *reinterpret_cast<float4*>(&bv[4]) = *reinterpret_cast<const float4*>(&Bs[cc][tm * 8 + 4]);
                #pragma unroll
                for (int r = 0; r < 8; ++r)
                    #pragma unroll
                    for (int j = 0; j < 8; ++j)
                        acc[r][j] = fmaf(a[r], bv[j], acc[r][j]);
            }
        }
        float it[8];
        *reinterpret_cast<float4*>(&it[0]) = *reinterpret_cast<const float4*>(invt + mt + tm * 8);
        *reinterpret_cast<float4*>(&it[4]) = *reinterpret_cast<const float4*>(invt + mt + tm * 8 + 4);
        int mg0 = chunk * MLEN + mt + tm * 8;
        float vt = (float)(mg0 >> 8);
        float ub = (float)(tm * 8);
        #pragma unroll
        for (int r = 0; r < 8; ++r) {
            float L[8];
            #pragma unroll
            for (int j = 0; j < 8; ++j) L[j] = acc[r][j] * (sA[r] * it[j]);
            float tmax = L[0];
            #pragma unroll
            for (int j = 1; j < 8; ++j) tmax = fmaxf(tmax, L[j]);
            #pragma unroll
            for (int o = 1; o < 32; o <<= 1) tmax = fmaxf(tmax, __shfl_xor(tmax, o));
            float newm = fmaxf(mx[r], tmax);
            float ts = 0.f, tu = 0.f;
            #pragma unroll
            for (int j = 0; j < 8; ++j) {
                float pz = __expf(L[j] - newm);
                ts += pz;
                tu = fmaf(pz, ub + (float)j, tu);
            }
            #pragma unroll
            for (int o = 1; o < 32; o <<= 1) {
                ts += __shfl_xor(ts, o);
                tu += __shfl_xor(tu, o);
            }
            float f = __expf(mx[r] - newm);
            s[r]  = fmaf(s[r], f, ts);
            su[r] = fmaf(su[r], f, tu);
            sv[r] = fmaf(sv[r], f, vt * ts);
            mx[r] = newm;
        }
    }
    if (tm == 0) {
        #pragma unroll
        for (int r = 0; r < 8; ++r) {
            int n = nbase + tn * 8 + r;
            float4 o4 = make_float4(mx[r], s[r], su[r], sv[r]);
            *reinterpret_cast<float4*>(part + ((size_t)(b * NN + n) * MCHUNKS + chunk) * 4) = o4;
        }
    }
}

__global__ void fb_finish(const float* __restrict__ kscores,
                          const float* __restrict__ kdesc,
                          const float* __restrict__ sdense,
                          const float* __restrict__ desc,
                          const float* __restrict__ ws,
                          float* __restrict__ out) {
    int bn = blockIdx.x;
    int b = bn >> 9, n = bn & 511;
    int tid = threadIdx.x;
    __shared__ float swf[8];
    __shared__ int sidx[4];
    __shared__ float red[4];
    if (tid == 0) {
        const float* pp = ws + WS_PART + (size_t)bn * MCHUNKS * 4;
        float M = -1e30f;
        for (int k = 0; k < MCHUNKS; ++k) M = fmaxf(M, pp[4 * k]);
        float S = 0.f, SU = 0.f, SV = 0.f;
        for (int k = 0; k < MCHUNKS; ++k) {
            float f = __expf(pp[4 * k] - M);
            S  = fmaf(pp[4 * k + 1], f, S);
            SU = fmaf(pp[4 * k + 2], f, SU);
            SV = fmaf(pp[4 * k + 3], f, SV);
        }
        float u = SU / S, v = SV / S;
        out[bn * 2 + 0] = u;
        out[bn * 2 + 1] = v;
        float uc = fminf(fmaxf(u, 0.f), 255.f);
        float vc = fminf(fmaxf(v, 0.f), 255.f);
        float u0 = floorf(uc), v0 = floorf(vc);
        float u1 = fminf(u0 + 1.f, 255.f), v1 = fminf(v0 + 1.f, 255.f);
        float wu = uc - u0, wv = vc - v0;
        int i00 = (int)v0 * WW + (int)u0;
        int i01 = (int)v0 * WW + (int)u1;
        int i10 = (int)v1 * WW + (int)u0;
        int i11 = (int)v1 * WW + (int)u1;
        float w00 = (1.f - wv) * (1.f - wu), w01 = (1.f - wv) * wu;
        float w10 = wv * (1.f - wu),         w11 = wv * wu;
        const float* sd = sdense + (size_t)(2 * b + 1) * HWD;
        float ps = w00 * sd[i00] + w01 * sd[i01] + w10 * sd[i10] + w11 * sd[i11];
        const float* it = ws + WS_INVT + (size_t)b * HWD;
        swf[0] = w00 * it[i00]; swf[1] = w01 * it[i01];
        swf[2] = w10 * it[i10]; swf[3] = w11 * it[i11];
        swf[4] = ps;
        sidx[0] = i00; sidx[1] = i01; sidx[2] = i10; sidx[3] = i11;
    }
    __syncthreads();
    int c = tid;
    const float* dcol = desc + (size_t)(2 * b + 1) * CC * HWD + (size_t)c * HWD;
    float pd = swf[0] * dcol[sidx[0]] + swf[1] * dcol[sidx[1]]
             + swf[2] * dcol[sidx[2]] + swf[3] * dcol[sidx[3]];
    float sc = kdesc[(size_t)(2 * b) * CC * NN + (size_t)c * NN + n];
    float t = pd * sc;
    #pragma unroll
    for (int o = 32; o > 0; o >>= 1) t += __shfl_xor(t, o);
    if ((tid & 63) == 0) red[tid >> 6] = t;
    __syncthreads();
    if (tid == 0) {
        float dot = red[0] + red[1] + red[2] + red[3];
        float invs = ws[WS_INVS + b * NN + n];
        float dms = dot * invs * (1.0f / 256.0f);
        float wgt = 0.5f * (dms + 1.0f) * kscores[(size_t)(2 * b) * NN + n] * swf[4];
        out[BQ * NN * 2 + bn] = wgt;
    }
}

// ===================================================================================
extern "C" void kernel_launch(void* const* d_in, const int* in_sizes, int n_in,
                              void* d_out, int out_size, void* d_ws, size_t ws_size,
                              hipStream_t stream) {
    const float* kscores = (const float*)d_in[0];  // (8,1,512)
    const float* kdesc   = (const float*)d_in[1];  // (8,256,512)
    const float* sdense  = (const float*)d_in[2];  // (8,1,256,256)
    const float* desc    = (const float*)d_in[3];  // (8,256,256,256)
    float* out = (float*)d_out;
    char* wsb = (char*)d_ws;
    float* wsf = (float*)d_ws;

    if (ws_size >= WS_REQ) {
        _Float16* AH = (_Float16*)(wsb + OB_AH);
        _Float16* BH = (_Float16*)(wsb + OB_BH);
        float* part = (float*)(wsb + OB_PART);

        // combined prep: x<1024 -> B tiles (odd desc batches), x>=1024 -> A tiles
        hipLaunchKernelGGL(k_prep16, dim3(1024 + NN / 64, BQ), dim3(256), 0, stream,
                           desc, kdesc, BH, AH);
        hipLaunchKernelGGL(k_main3, dim3(256), dim3(512), 0, stream,
                           AH, BH, part);
        hipLaunchKernelGGL(k_finish3, dim3(BQ * NN), dim3(256), 0, stream,
                           kscores, sdense, AH, BH, part, out);
    } else {
        float* ws = wsf;
        hipLaunchKernelGGL(fb_invt, dim3(BQ * HWD / 4 / 256), dim3(256), 0, stream, desc, ws);
        hipLaunchKernelGGL(fb_invs, dim3(BQ * NN / 256), dim3(256), 0, stream, kdesc, ws);
        hipLaunchKernelGGL(fb_main, dim3(MCHUNKS, NN / TN, BQ), dim3(256), 0, stream,
                           kdesc, desc, ws, ws + WS_PART);
        hipLaunchKernelGGL(fb_finish, dim3(BQ * NN), dim3(256), 0, stream,
                           kscores, kdesc, sdense, desc, ws, out);
    }
}

// Round 11
// 173.181 us; speedup vs baseline: 1.0975x; 1.0635x over previous
//
#include <hip/hip_runtime.h>
#include <math.h>

#define BQ 4
#define CC 256
#define NN 512
#define HWD 65536
#define WW 256

typedef __attribute__((ext_vector_type(8))) _Float16 f16x8;
typedef __attribute__((ext_vector_type(4))) float f32x4;

// ---------------- fast-path ws byte offsets ----------------
#define OB_PART 1056768u          // [4*512][16][3] f32
#define OB_AH   2097152u          // [4][8][512][32] f16 (1 MB)
#define OB_BH   4194304u          // [4][8][65536][32] f16 (128 MB)
#define WS_REQ  138412032ull

#define GLDS16(g, l) __builtin_amdgcn_global_load_lds( \
    (const __attribute__((address_space(1))) void*)(g), \
    (__attribute__((address_space(3))) void*)(l), 16, 0, 0)

__device__ inline unsigned pk2h(float x0, float x1) {
    _Float16 h0 = (_Float16)x0, h1 = (_Float16)x1;
    unsigned short u0 = __builtin_bit_cast(unsigned short, h0);
    unsigned short u1 = __builtin_bit_cast(unsigned short, h1);
    return (unsigned)u0 | ((unsigned)u1 << 16);
}

// ================= prep: normalize + fp16 convert + k-blocked pack (A and B) =========
// blockIdx.x < 1024: B tile (odd batches of desc); >= 1024: A tile (even of kdesc).
__global__ __launch_bounds__(256) void k_prep16(
    const float* __restrict__ descB, const float* __restrict__ descA,
    _Float16* __restrict__ outB, _Float16* __restrict__ outA) {
    __shared__ float raw[CC * 64];
    __shared__ float sinv[64];
    int b = blockIdx.y;
    int bx = blockIdx.x;
    int tid = threadIdx.x;

    const float* S;
    _Float16* outH;
    int ld, rows_tot, mb;
    if (bx < 1024) {
        S = descB + (size_t)(2 * b + 1) * CC * HWD;
        outH = outB; ld = HWD; rows_tot = HWD; mb = bx * 64;
    } else {
        S = descA + (size_t)(2 * b) * CC * NN;
        outH = outA; ld = NN; rows_tot = NN; mb = (bx - 1024) * 64;
    }

    #pragma unroll
    for (int it = 0; it < 16; ++it) {
        int c = it * 16 + (tid >> 4);
        int m4 = (tid & 15) * 4;
        float4 v = *reinterpret_cast<const float4*>(S + (size_t)c * ld + mb + m4);
        *reinterpret_cast<float4*>(&raw[c * 64 + (m4 ^ (c & 60))]) = v;
    }
    __syncthreads();
    {
        int m = tid >> 2, part = tid & 3;
        float acc = 0.f;
        for (int i = 0; i < 64; ++i) {
            int c = part * 64 + i;
            float x = raw[c * 64 + (m ^ (c & 60))];
            acc = fmaf(x, x, acc);
        }
        acc += __shfl_xor(acc, 1);
        acc += __shfl_xor(acc, 2);
        if (part == 0) sinv[m] = 1.0f / fmaxf(sqrtf(acc), 1e-12f);
    }
    __syncthreads();
    int m = tid & 63, sub = tid >> 6;
    float iv = sinv[m];
    for (int kc = 0; kc < 8; ++kc) {
        int c0 = kc * 32 + sub * 8;
        unsigned hh[4];
        #pragma unroll
        for (int jp = 0; jp < 4; ++jp) {
            int c = c0 + jp * 2;
            int c1 = c + 1;
            float x0 = raw[c * 64 + (m ^ (c & 60))] * iv;
            float x1 = raw[c1 * 64 + (m ^ (c1 & 60))] * iv;
            hh[jp] = pk2h(x0, x1);
        }
        size_t base = ((size_t)(b * 8 + kc) * rows_tot + mb + m) * 32 + sub * 8;
        *reinterpret_cast<uint4*>(outH + base) = make_uint4(hh[0], hh[1], hh[2], hh[3]);
    }
}

// ================= main: single-pass fp16 MFMA GEMM + fused fixed-max softmax =======
// Grid 256 blocks: block = (b, chunk, nt). Tile 128n x 256m/step, m-chunk 4096.
// A (8 kc slices) resident in LDS (64KB) staged once -> NO barriers in main loop.
// B frags register-direct from global, 4 reg buffers, distance-2 prefetch, vmcnt(8).
// [r11: verbatim revert to the r7 optimum -- r9 (1x8 layout, 190us) and r10
//  (distance-3, 184us) both regressed vs this configuration's 173.7us.]
__global__ __launch_bounds__(512, 2) void k_main3(
    const _Float16* __restrict__ Ah, const _Float16* __restrict__ Bh,
    float* __restrict__ part) {
    __shared__ __align__(16) char smem[65536];

    int p = blockIdx.x;
    int xcd = p & 7, slot = p >> 3;
    int g = slot >> 2, nt = slot & 3;
    int pair = xcd * 8 + g;
    int bb = pair >> 4, chunk = pair & 15;
    int nbase = nt * 128;

    int tid = threadIdx.x;
    int w = tid >> 6, lane = tid & 63;
    int wn = w >> 2, wm = w & 3;
    int lrow = lane & 15, lkh = lane >> 4;
    int key = (lrow >> 1) & 3;

    // A staging: linear LDS dest + pre-swizzled source
    int sA = tid * 16;
    int rA = sA >> 6, slA = (sA >> 4) & 3;
    int seA = (rA << 5) + ((slA ^ ((rA >> 1) & 3)) << 3);
    int wb = w * 1024;

    // A frag ds_read offset (f16 elems): bank-swizzled
    int aoff = ((wn * 64 + lrow) << 5) + ((lkh ^ key) << 3);
    // B frag global offset (f16 elems): linear
    int boffG = ((wm * 64 + lrow) << 5) + (lkh << 3);

    // ---- prologue: stage all A slices; load B for phases 0,1 ----
    #pragma unroll
    for (int kc = 0; kc < 8; ++kc) {
        size_t aB = ((size_t)(bb * 8 + kc) * 512 + nbase) * 32;
        GLDS16(Ah + aB + seA, smem + kc * 8192 + wb);
    }
    f16x8 breg[4][4];
    #define BLOAD(buf, ms, kc) do {                                             \
        size_t bB = ((size_t)(bb * 8 + (kc)) * 65536 + (size_t)chunk * 4096     \
                     + (size_t)(ms) * 256) * 32 + boffG;                        \
        const _Float16* bp = Bh + bB;                                           \
        breg[buf][0] = *reinterpret_cast<const f16x8*>(bp);                     \
        breg[buf][1] = *reinterpret_cast<const f16x8*>(bp + 512);               \
        breg[buf][2] = *reinterpret_cast<const f16x8*>(bp + 1024);              \
        breg[buf][3] = *reinterpret_cast<const f16x8*>(bp + 1536);              \
    } while (0)
    BLOAD(0, 0, 0);
    BLOAD(1, 0, 1);
    asm volatile("s_waitcnt vmcnt(0)" ::: "memory");
    __syncthreads();

    float s_[4][4], su_[4][4], sv_[4][4];
    #pragma unroll
    for (int i = 0; i < 4; ++i)
        #pragma unroll
        for (int j = 0; j < 4; ++j) { s_[i][j] = 0.f; su_[i][j] = 0.f; sv_[i][j] = 0.f; }

    for (int ms = 0; ms < 16; ++ms) {
        f32x4 acc[4][4];
        #pragma unroll
        for (int i = 0; i < 4; ++i)
            #pragma unroll
            for (int j = 0; j < 4; ++j) acc[i][j] = (f32x4){0.f, 0.f, 0.f, 0.f};

        #pragma unroll
        for (int kc = 0; kc < 8; ++kc) {
            // ---- A frag ds_reads issued BEFORE the vmcnt fence (LDS is stable) ----
            const _Float16* base = (const _Float16*)(smem + kc * 8192);
            f16x8 ah[4];
            #pragma unroll
            for (int rt = 0; rt < 4; ++rt)
                ah[rt] = *reinterpret_cast<const f16x8*>(base + aoff + rt * 512);

            // ---- prefetch phase p+2 into breg[(kc+2)&3]; counted wait ----
            // (phase p = ms*8+kc; kc&3 == p&3 because 8 == 0 mod 4)
            int nkc = kc + 2;
            int nms = ms + (nkc >> 3);
            nkc &= 7;
            if (nms < 16) {
                BLOAD((kc + 2) & 3, nms, nkc);
                asm volatile("s_waitcnt vmcnt(8)" ::: "memory");   // breg[kc&3] ready
            } else if (kc == 6) {
                asm volatile("s_waitcnt vmcnt(4)" ::: "memory");
            } else {
                asm volatile("s_waitcnt vmcnt(0)" ::: "memory");
            }

            __builtin_amdgcn_s_setprio(1);
            #pragma unroll
            for (int rt = 0; rt < 4; ++rt)
                #pragma unroll
                for (int ct = 0; ct < 4; ++ct)
                    acc[rt][ct] = __builtin_amdgcn_mfma_f32_16x16x32_f16(
                        ah[rt], breg[kc & 3][ct], acc[rt][ct], 0, 0, 0);
            __builtin_amdgcn_s_setprio(0);
        }

        // fused softmax accumulation: p = exp(100*(dot-1)), fixed max (cos <= 1)
        float vstep = (float)(chunk * 16 + ms);
        #pragma unroll
        for (int rt = 0; rt < 4; ++rt) {
            #pragma unroll
            for (int reg = 0; reg < 4; ++reg) {
                float ts = 0.f, tu = 0.f;
                #pragma unroll
                for (int ct = 0; ct < 4; ++ct) {
                    float L = acc[rt][ct][reg];
                    float pz = __expf(fmaf(L, 100.f, -100.f));
                    ts += pz;
                    tu = fmaf(pz, (float)(wm * 64 + ct * 16 + lrow), tu);
                }
                s_[rt][reg] += ts;
                su_[rt][reg] += tu;
                sv_[rt][reg] = fmaf(vstep, ts, sv_[rt][reg]);
            }
        }
    }
    #undef BLOAD

    // ---- cross-lane (16 lrow) reduce, then cross-wm reduce through LDS ----
    __syncthreads();   // all waves done with A slices before smem reuse
    float* lred = (float*)smem;   // [8 waves][64 n_local][3]
    #pragma unroll
    for (int rt = 0; rt < 4; ++rt) {
        #pragma unroll
        for (int reg = 0; reg < 4; ++reg) {
            float a = s_[rt][reg], b2 = su_[rt][reg], c2 = sv_[rt][reg];
            #pragma unroll
            for (int o = 1; o < 16; o <<= 1) {
                a += __shfl_xor(a, o);
                b2 += __shfl_xor(b2, o);
                c2 += __shfl_xor(c2, o);
            }
            if (lrow == 0) {
                int nl = rt * 16 + lkh * 4 + reg;
                lred[(w * 64 + nl) * 3 + 0] = a;
                lred[(w * 64 + nl) * 3 + 1] = b2;
                lred[(w * 64 + nl) * 3 + 2] = c2;
            }
        }
    }
    __syncthreads();
    if (tid < 128) {
        int wnl = tid >> 6, nl = tid & 63;
        float a = 0.f, b2 = 0.f, c2 = 0.f;
        #pragma unroll
        for (int q = 0; q < 4; ++q) {
            const float* p2 = &lred[((wnl * 4 + q) * 64 + nl) * 3];
            a += p2[0]; b2 += p2[1]; c2 += p2[2];
        }
        int n = nbase + wnl * 64 + nl;
        float* dst = part + ((size_t)(bb * 512 + n) * 16 + chunk) * 3;
        dst[0] = a; dst[1] = b2; dst[2] = c2;
    }
}

// ================= finish: merge partials + coords + packed-f16 bilinear dot =========
__global__ __launch_bounds__(256) void k_finish3(
    const float* __restrict__ kscores, const float* __restrict__ sdense,
    const _Float16* __restrict__ AH, const _Float16* __restrict__ BH,
    const float* __restrict__ part, float* __restrict__ out) {
    int bn = blockIdx.x;
    int b = bn >> 9, n = bn & 511;
    int tid = threadIdx.x;
    __shared__ float sw[4];
    __shared__ int sm[4];
    __shared__ float sps;
    __shared__ float red[4];

    if (tid == 0) {
        const float* pp = part + (size_t)bn * 48;
        float S = 0.f, SU = 0.f, SV = 0.f;
        for (int k = 0; k < 16; ++k) {
            S += pp[k * 3]; SU += pp[k * 3 + 1]; SV += pp[k * 3 + 2];
        }
        float u = SU / S, v = SV / S;
        out[bn * 2 + 0] = u;
        out[bn * 2 + 1] = v;

        float uc = fminf(fmaxf(u, 0.f), 255.f);
        float vc = fminf(fmaxf(v, 0.f), 255.f);
        float u0 = floorf(uc), v0 = floorf(vc);
        float u1 = fminf(u0 + 1.f, 255.f), v1 = fminf(v0 + 1.f, 255.f);
        float wu = uc - u0, wv = vc - v0;
        int i00 = (int)v0 * WW + (int)u0;
        int i01 = (int)v0 * WW + (int)u1;
        int i10 = (int)v1 * WW + (int)u0;
        int i11 = (int)v1 * WW + (int)u1;
        sw[0] = (1.f - wv) * (1.f - wu); sw[1] = (1.f - wv) * wu;
        sw[2] = wv * (1.f - wu);         sw[3] = wv * wu;
        sm[0] = i00; sm[1] = i01; sm[2] = i10; sm[3] = i11;

        const float* sd = sdense + (size_t)(2 * b + 1) * HWD;
        sps = sw[0] * sd[i00] + sw[1] * sd[i01] + sw[2] * sd[i10] + sw[3] * sd[i11];
    }
    __syncthreads();

    // packed, normalized f16 reads: column of AH / 4 corners of BH (8x64B contiguous)
    int kc = tid >> 5, e = tid & 31;
    float a = (float)AH[((size_t)(b * 8 + kc) * 512 + n) * 32 + e];
    float pdc = 0.f;
    #pragma unroll
    for (int wq = 0; wq < 4; ++wq) {
        float bv = (float)BH[((size_t)(b * 8 + kc) * 65536 + sm[wq]) * 32 + e];
        pdc = fmaf(sw[wq], bv, pdc);
    }
    float t = a * pdc;
    #pragma unroll
    for (int o = 1; o < 64; o <<= 1) t += __shfl_xor(t, o);
    if ((tid & 63) == 0) red[tid >> 6] = t;
    __syncthreads();
    if (tid == 0) {
        float dot = red[0] + red[1] + red[2] + red[3];
        float dms = dot * (1.0f / 256.0f);
        float wgt = 0.5f * (dms + 1.0f) * kscores[(size_t)(2 * b) * NN + n] * sps;
        out[BQ * NN * 2 + bn] = wgt;
    }
}

// ===================================================================================
// ======================= fallback path (round-1, small ws) =========================
// ===================================================================================
#define MCHUNKS 16
#define MLEN (HWD / MCHUNKS)
#define TN 64
#define TM 256
#define CK 16
#define WS_INVT 0
#define WS_INVS (BQ * HWD)
#define WS_PART (WS_INVS + BQ * NN)

__global__ void fb_invt(const float* __restrict__ desc, float* __restrict__ ws) {
    int gid = blockIdx.x * blockDim.x + threadIdx.x;
    int b = gid >> 14;
    int m4 = (gid & 16383) << 2;
    const float* base = desc + (size_t)(2 * b + 1) * CC * HWD + m4;
    float ax = 0.f, ay = 0.f, az = 0.f, aw = 0.f;
    #pragma unroll 4
    for (int c = 0; c < CC; ++c) {
        float4 v = *reinterpret_cast<const float4*>(base + (size_t)c * HWD);
        ax = fmaf(v.x, v.x, ax); ay = fmaf(v.y, v.y, ay);
        az = fmaf(v.z, v.z, az); aw = fmaf(v.w, v.w, aw);
    }
    float4 r;
    r.x = 1.0f / fmaxf(sqrtf(ax), 1e-12f);
    r.y = 1.0f / fmaxf(sqrtf(ay), 1e-12f);
    r.z = 1.0f / fmaxf(sqrtf(az), 1e-12f);
    r.w = 1.0f / fmaxf(sqrtf(aw), 1e-12f);
    *reinterpret_cast<float4*>(ws + WS_INVT + b * HWD + m4) = r;
}

__global__ void fb_invs(const float* __restrict__ kdesc, float* __restrict__ ws) {
    int gid = blockIdx.x * blockDim.x + threadIdx.x;
    int b = gid >> 9;
    int n = gid & 511;
    const float* base = kdesc + (size_t)(2 * b) * CC * NN + n;
    float acc = 0.f;
    for (int c = 0; c < CC; ++c) {
        float v = base[(size_t)c * NN];
        acc = fmaf(v, v, acc);
    }
    ws[WS_INVS + b * NN + n] = 1.0f / fmaxf(sqrtf(acc), 1e-12f);
}

__global__ __launch_bounds__(256) void fb_main(
    const float* __restrict__ kdesc, const float* __restrict__ desc,
    const float* __restrict__ ws, float* __restrict__ part) {
    __shared__ float As[CK][TN];
    __shared__ float Bs[CK][TM];
    int chunk = blockIdx.x, ntile = blockIdx.y, b = blockIdx.z;
    int tid = threadIdx.x;
    int tn = tid >> 5, tm = tid & 31;
    int nbase = ntile * TN;
    const float* Ag = kdesc + (size_t)(2 * b) * CC * NN + nbase;
    const float* Bg = desc + (size_t)(2 * b + 1) * CC * HWD + (size_t)chunk * MLEN;
    const float* invt = ws + WS_INVT + (size_t)b * HWD + (size_t)chunk * MLEN;
    float sA[8];
    #pragma unroll
    for (int r = 0; r < 8; ++r)
        sA[r] = ws[WS_INVS + b * NN + nbase + tn * 8 + r] * 100.0f;
    float mx[8], s[8], su[8], sv[8];
    #pragma unroll
    for (int r = 0; r < 8; ++r) { mx[r] = -1e30f; s[r] = 0.f; su[r] = 0.f; sv[r] = 0.f; }
    for (int mt = 0; mt < MLEN; mt += TM) {
        float acc[8][8];
        #pragma unroll
        for (int r = 0; r < 8; ++r)
            #pragma unroll
            for (int j = 0; j < 8; ++j) acc[r][j] = 0.f;
        for (int c0 = 0; c0 < CC; c0 += CK) {
            int ca = tid >> 4, na = (tid & 15) << 2;
            float4 va = *reinterpret_cast<const float4*>(Ag + (size_t)(c0 + ca) * NN + na);
            int cb = tid >> 6, mb = (tid & 63) << 2;
            float4 vb[4];
            #pragma unroll
            for (int i = 0; i < 4; ++i)
                vb[i] = *reinterpret_cast<const float4*>(Bg + (size_t)(c0 + cb + 4 * i) * HWD + mt + mb);
            __syncthreads();
            *reinterpret_cast<float4*>(&As[ca][na]) = va;
            #pragma unroll
            for (int i = 0; i < 4; ++i)
                *reinterpret_cast<float4*>(&Bs[cb + 4 * i][mb]) = vb[i];
            __syncthreads();
            #pragma unroll
            for (int cc = 0; cc < CK; ++cc) {
                float a[8], bv[8];
                *reinterpret_cast<float4*>(&a[0]) = *reinterpret_cast<const float4*>(&As[cc][tn * 8]);
                *reinterpret_cast<float4*>(&a[4]) = *reinterpret_cast<const float4*>(&As[cc][tn * 8 + 4]);
                *reinterpret_cast<float4*>(&bv[0]) = *reinterpret_cast<const float4*>(&Bs[cc][tm * 8]);
                *reinterpret_cast<float4*>(&bv[4]) = *reinterpret_cast<const float4*>(&Bs[cc][tm * 8 + 4]);
                #pragma unroll
                for (int r = 0; r < 8; ++r)
                    #pragma unroll
                    for (int j = 0; j < 8; ++j)
                        acc[r][j] = fmaf(a[r], bv[j], acc[r][j]);
            }
        }
        float it[8];
        *reinterpret_cast<float4*>(&it[0]) = *reinterpret_cast<const float4*>(invt + mt + tm * 8);
        *reinterpret_cast<float4*>(&it[4]) = *reinterpret_cast<const float4*>(invt + mt + tm * 8 + 4);
        int mg0 = chunk * MLEN + mt + tm * 8;
        float vt = (float)(mg0 >> 8);
        float ub = (float)(tm * 8);
        #pragma unroll
        for (int r = 0; r < 8; ++r) {
            float L[8];
            #pragma unroll
            for (int j = 0; j < 8; ++j) L[j] = acc[r][j] * (sA[r] * it[j]);
            float tmax = L[0];
            #pragma unroll
            for (int j = 1; j < 8; ++j) tmax = fmaxf(tmax, L[j]);
            #pragma unroll
            for (int o = 1; o < 32; o <<= 1) tmax = fmaxf(tmax, __shfl_xor(tmax, o));
            float newm = fmaxf(mx[r], tmax);
            float ts = 0.f, tu = 0.f;
            #pragma unroll
            for (int j = 0; j < 8; ++j) {
                float pz = __expf(L[j] - newm);
                ts += pz;
                tu = fmaf(pz, ub + (float)j, tu);
            }
            #pragma unroll
            for (int o = 1; o < 32; o <<= 1) {
                ts += __shfl_xor(ts, o);
                tu += __shfl_xor(tu, o);
            }
            float f = __expf(mx[r] - newm);
            s[r]  = fmaf(s[r], f, ts);
            su[r] = fmaf(su[r], f, tu);
            sv[r] = fmaf(sv[r], f, vt * ts);
            mx[r] = newm;
        }
    }
    if (tm == 0) {
        #pragma unroll
        for (int r = 0; r < 8; ++r) {
            int n = nbase + tn * 8 + r;
            float4 o4 = make_float4(mx[r], s[r], su[r], sv[r]);
            *reinterpret_cast<float4*>(part + ((size_t)(b * NN + n) * MCHUNKS + chunk) * 4) = o4;
        }
    }
}

__global__ void fb_finish(const float* __restrict__ kscores,
                          const float* __restrict__ kdesc,
                          const float* __restrict__ sdense,
                          const float* __restrict__ desc,
                          const float* __restrict__ ws,
                          float* __restrict__ out) {
    int bn = blockIdx.x;
    int b = bn >> 9, n = bn & 511;
    int tid = threadIdx.x;
    __shared__ float swf[8];
    __shared__ int sidx[4];
    __shared__ float red[4];
    if (tid == 0) {
        const float* pp = ws + WS_PART + (size_t)bn * MCHUNKS * 4;
        float M = -1e30f;
        for (int k = 0; k < MCHUNKS; ++k) M = fmaxf(M, pp[4 * k]);
        float S = 0.f, SU = 0.f, SV = 0.f;
        for (int k = 0; k < MCHUNKS; ++k) {
            float f = __expf(pp[4 * k] - M);
            S  = fmaf(pp[4 * k + 1], f, S);
            SU = fmaf(pp[4 * k + 2], f, SU);
            SV = fmaf(pp[4 * k + 3], f, SV);
        }
        float u = SU / S, v = SV / S;
        out[bn * 2 + 0] = u;
        out[bn * 2 + 1] = v;
        float uc = fminf(fmaxf(u, 0.f), 255.f);
        float vc = fminf(fmaxf(v, 0.f), 255.f);
        float u0 = floorf(uc), v0 = floorf(vc);
        float u1 = fminf(u0 + 1.f, 255.f), v1 = fminf(v0 + 1.f, 255.f);
        float wu = uc - u0, wv = vc - v0;
        int i00 = (int)v0 * WW + (int)u0;
        int i01 = (int)v0 * WW + (int)u1;
        int i10 = (int)v1 * WW + (int)u0;
        int i11 = (int)v1 * WW + (int)u1;
        float w00 = (1.f - wv) * (1.f - wu), w01 = (1.f - wv) * wu;
        float w10 = wv * (1.f - wu),         w11 = wv * wu;
        const float* sd = sdense + (size_t)(2 * b + 1) * HWD;
        float ps = w00 * sd[i00] + w01 * sd[i01] + w10 * sd[i10] + w11 * sd[i11];
        const float* it = ws + WS_INVT + (size_t)b * HWD;
        swf[0] = w00 * it[i00]; swf[1] = w01 * it[i01];
        swf[2] = w10 * it[i10]; swf[3] = w11 * it[i11];
        swf[4] = ps;
        sidx[0] = i00; sidx[1] = i01; sidx[2] = i10; sidx[3] = i11;
    }
    __syncthreads();
    int c = tid;
    const float* dcol = desc + (size_t)(2 * b + 1) * CC * HWD + (size_t)c * HWD;
    float pd = swf[0] * dcol[sidx[0]] + swf[1] * dcol[sidx[1]]
             + swf[2] * dcol[sidx[2]] + swf[3] * dcol[sidx[3]];
    float sc = kdesc[(size_t)(2 * b) * CC * NN + (size_t)c * NN + n];
    float t = pd * sc;
    #pragma unroll
    for (int o = 32; o > 0; o >>= 1) t += __shfl_xor(t, o);
    if ((tid & 63) == 0) red[tid >> 6] = t;
    __syncthreads();
    if (tid == 0) {
        float dot = red[0] + red[1] + red[2] + red[3];
        float invs = ws[WS_INVS + b * NN + n];
        float dms = dot * invs * (1.0f / 256.0f);
        float wgt = 0.5f * (dms + 1.0f) * kscores[(size_t)(2 * b) * NN + n] * swf[4];
        out[BQ * NN * 2 + bn] = wgt;
    }
}

// ===================================================================================
extern "C" void kernel_launch(void* const* d_in, const int* in_sizes, int n_in,
                              void* d_out, int out_size, void* d_ws, size_t ws_size,
                              hipStream_t stream) {
    const float* kscores = (const float*)d_in[0];  // (8,1,512)
    const float* kdesc   = (const float*)d_in[1];  // (8,256,512)
    const float* sdense  = (const float*)d_in[2];  // (8,1,256,256)
    const float* desc    = (const float*)d_in[3];  // (8,256,256,256)
    float* out = (float*)d_out;
    char* wsb = (char*)d_ws;
    float* wsf = (float*)d_ws;

    if (ws_size >= WS_REQ) {
        _Float16* AH = (_Float16*)(wsb + OB_AH);
        _Float16* BH = (_Float16*)(wsb + OB_BH);
        float* part = (float*)(wsb + OB_PART);

        // combined prep: x<1024 -> B tiles (odd desc batches), x>=1024 -> A tiles
        hipLaunchKernelGGL(k_prep16, dim3(1024 + NN / 64, BQ), dim3(256), 0, stream,
                           desc, kdesc, BH, AH);
        hipLaunchKernelGGL(k_main3, dim3(256), dim3(512), 0, stream,
                           AH, BH, part);
        hipLaunchKernelGGL(k_finish3, dim3(BQ * NN), dim3(256), 0, stream,
                           kscores, sdense, AH, BH, part, out);
    } else {
        float* ws = wsf;
        hipLaunchKernelGGL(fb_invt, dim3(BQ * HWD / 4 / 256), dim3(256), 0, stream, desc, ws);
        hipLaunchKernelGGL(fb_invs, dim3(BQ * NN / 256), dim3(256), 0, stream, kdesc, ws);
        hipLaunchKernelGGL(fb_main, dim3(MCHUNKS, NN / TN, BQ), dim3(256), 0, stream,
                           kdesc, desc, ws, ws + WS_PART);
        hipLaunchKernelGGL(fb_finish, dim3(BQ * NN), dim3(256), 0, stream,
                           kscores, kdesc, sdense, desc, ws, out);
    }
}